// Round 2
// baseline (267.995 us; speedup 1.0000x reference)
//
#include <hip/hip_runtime.h>
#include <math.h>

#define MAP 56
#define KST 10.0f
#define BATCH 16384
#define DIM 1024
#define HID 512

typedef float floatx4 __attribute__((ext_vector_type(4)));

// ---------------------------------------------------------------------------
// Kernel 1: fold W1@W2 -> WeffT [3][1024] (transposed for float4 reads),
// b1@W2 + b2 -> beff [3]. Grid: 1025 blocks x 64 threads. ~3 us.
// ---------------------------------------------------------------------------
__global__ __launch_bounds__(64) void fold_weights(
    const float* __restrict__ W1, const float* __restrict__ b1,
    const float* __restrict__ W2, const float* __restrict__ b2,
    float* __restrict__ WeffT, float* __restrict__ beff)
{
    const int d = blockIdx.x;        // 0..1023 = W1 row, 1024 = bias row
    const int lane = threadIdx.x;
    const float* row = (d < DIM) ? (W1 + (size_t)d * HID) : b1;

    float a0 = 0.f, a1 = 0.f, a2 = 0.f;
    for (int h = lane; h < HID; h += 64) {
        const float w = row[h];
        a0 += w * W2[h * 3 + 0];
        a1 += w * W2[h * 3 + 1];
        a2 += w * W2[h * 3 + 2];
    }
    #pragma unroll
    for (int off = 32; off; off >>= 1) {
        a0 += __shfl_down(a0, off, 64);
        a1 += __shfl_down(a1, off, 64);
        a2 += __shfl_down(a2, off, 64);
    }
    if (lane == 0) {
        if (d < DIM) {
            WeffT[0 * DIM + d] = a0;
            WeffT[1 * DIM + d] = a1;
            WeffT[2 * DIM + d] = a2;
        } else {
            beff[0] = a0 + b2[0];
            beff[1] = a1 + b2[1];
            beff[2] = a2 + b2[2];
        }
    }
}

// ---------------------------------------------------------------------------
// Kernel 2a (R2 split): pure-streaming GEMV. One row per wave, 4 waves/block,
// 4096 blocks. Low VGPR (3 accumulators, 16 float4 in flight), no barriers.
// Writes t4[B][4] (stride 4 for aligned float4 stores / loads downstream).
// Expected ~12 us (67 MB x-read at HBM rate).
// ---------------------------------------------------------------------------
__global__ __launch_bounds__(256) void gemv_kernel(
    const float* __restrict__ x, const float* __restrict__ WeffT,
    const float* __restrict__ beff, float* __restrict__ t4)
{
    const int tid  = threadIdx.x;
    const int wave = tid >> 6;
    const int lane = tid & 63;
    const int row  = blockIdx.x * 4 + wave;

    const float* xr = x + (size_t)row * DIM + 4 * lane;
    float a0 = 0.f, a1 = 0.f, a2 = 0.f;
    #pragma unroll
    for (int q = 0; q < 4; ++q) {
        const int off = 256 * q;
        const floatx4 w0 = *(const floatx4*)(WeffT + 0 * DIM + 4 * lane + off);
        const floatx4 w1 = *(const floatx4*)(WeffT + 1 * DIM + 4 * lane + off);
        const floatx4 w2 = *(const floatx4*)(WeffT + 2 * DIM + 4 * lane + off);
        const floatx4 xv = *(const floatx4*)(xr + off);
        a0 += xv.x * w0.x + xv.y * w0.y + xv.z * w0.z + xv.w * w0.w;
        a1 += xv.x * w1.x + xv.y * w1.y + xv.z * w1.z + xv.w * w1.w;
        a2 += xv.x * w2.x + xv.y * w2.y + xv.z * w2.z + xv.w * w2.w;
    }
    #pragma unroll
    for (int off = 32; off; off >>= 1) {
        a0 += __shfl_down(a0, off, 64);
        a1 += __shfl_down(a1, off, 64);
        a2 += __shfl_down(a2, off, 64);
    }
    if (lane == 0) {
        floatx4 o;
        o.x = a0 + beff[0];
        o.y = a1 + beff[1];
        o.z = a2 + beff[2];
        o.w = 0.f;
        *(floatx4*)(t4 + (size_t)row * 4) = o;
    }
}

// ---------------------------------------------------------------------------
// Kernel 2b (R2 split): render. One row per wave, 4 waves/block, 4096 blocks.
// NO __syncthreads: each wave owns its LDS strip [0..55]=Vx, [64..119]=Vy.
// 112 sigmoid-pairs per wave (2 passes), then 784 float4 coalesced stores.
// Tiny VGPR -> max occupancy; expected ~36 us (196 MiB write at HBM rate).
// ---------------------------------------------------------------------------
__global__ __launch_bounds__(256) void render_kernel(
    const float* __restrict__ t4, float* __restrict__ out)
{
    __shared__ float sV[4][128];   // per-wave strip: Vx at [0], Vy at [64] (16B aligned)

    const int tid  = threadIdx.x;
    const int wave = tid >> 6;
    const int lane = tid & 63;
    const int row  = blockIdx.x * 4 + wave;

    const floatx4 tv = *(const floatx4*)(t4 + (size_t)row * 4);
    const float hh = 0.5f * tv.z;

    #pragma unroll
    for (int p = 0; p < 2; ++p) {
        const int e = lane + 64 * p;
        if (e < 2 * MAP) {
            const int   isY = e >= MAP;
            const int   i   = isY ? e - MAP : e;
            const float tc  = isY ? tv.y : tv.x;
            const float u   = (float)i - tc;
            const float pp  = 1.0f / (1.0f + __expf(-KST * (u + hh)));
            const float mm  = 1.0f / (1.0f + __expf(-KST * (u - hh)));
            sV[wave][(isY ? 64 : 0) + i] = pp - mm;
        }
    }
    // Same-wave LDS RAW: wait for our own ds_writes; no cross-wave hazard,
    // so no __syncthreads. "memory" clobber pins the following ds_reads.
    asm volatile("s_waitcnt lgkmcnt(0)" ::: "memory");

    floatx4* ob = (floatx4*)(out + (size_t)row * (MAP * MAP));
    const floatx4* vy4 = (const floatx4*)&sV[wave][64];
    for (int g = lane; g < MAP * MAP / 4; g += 64) {   // 784 = 12*64 + 16
        const int   i  = g / (MAP / 4);
        const int   jq = g - i * (MAP / 4);
        const float vx = sV[wave][i];
        const floatx4 vy = vy4[jq];
        floatx4 o;
        o.x = vx * vy.x; o.y = vx * vy.y; o.z = vx * vy.z; o.w = vx * vy.w;
        ob[g] = o;
    }
}

extern "C" void kernel_launch(void* const* d_in, const int* in_sizes, int n_in,
                              void* d_out, int out_size, void* d_ws, size_t ws_size,
                              hipStream_t stream) {
    const float* x  = (const float*)d_in[0];   // [16384, 1024]
    const float* W1 = (const float*)d_in[1];   // [1024, 512]
    const float* b1 = (const float*)d_in[2];   // [512]
    const float* W2 = (const float*)d_in[3];   // [512, 3]
    const float* b2 = (const float*)d_in[4];   // [3]
    float* out = (float*)d_out;                // [16384, 56, 56]

    float* WeffT = (float*)d_ws;               // 3*1024 floats
    float* beff  = WeffT + 3 * DIM;            // 4 floats (1 pad)
    float* t4    = beff + 4;                   // 16384*4 floats, 16B-aligned

    fold_weights<<<DIM + 1, 64, 0, stream>>>(W1, b1, W2, b2, WeffT, beff);
    gemv_kernel<<<BATCH / 4, 256, 0, stream>>>(x, WeffT, beff, t4);
    render_kernel<<<BATCH / 4, 256, 0, stream>>>(t4, out);
}

// Round 3
// 266.783 us; speedup vs baseline: 1.0045x; 1.0045x over previous
//
#include <hip/hip_runtime.h>
#include <math.h>

#define MAP 56
#define KST 10.0f
#define BATCH 16384
#define DIM 1024
#define HID 512

typedef float floatx4 __attribute__((ext_vector_type(4)));

// ---------------------------------------------------------------------------
// Kernel 1: fold W1@W2 -> WeffT [3][1024] (transposed for float4 reads),
// b1@W2 + b2 -> beff [3]. Grid: 1025 blocks x 64 threads. ~3 us.
// ---------------------------------------------------------------------------
__global__ __launch_bounds__(64) void fold_weights(
    const float* __restrict__ W1, const float* __restrict__ b1,
    const float* __restrict__ W2, const float* __restrict__ b2,
    float* __restrict__ WeffT, float* __restrict__ beff)
{
    const int d = blockIdx.x;        // 0..1023 = W1 row, 1024 = bias row
    const int lane = threadIdx.x;
    const float* row = (d < DIM) ? (W1 + (size_t)d * HID) : b1;

    float a0 = 0.f, a1 = 0.f, a2 = 0.f;
    for (int h = lane; h < HID; h += 64) {
        const float w = row[h];
        a0 += w * W2[h * 3 + 0];
        a1 += w * W2[h * 3 + 1];
        a2 += w * W2[h * 3 + 2];
    }
    #pragma unroll
    for (int off = 32; off; off >>= 1) {
        a0 += __shfl_down(a0, off, 64);
        a1 += __shfl_down(a1, off, 64);
        a2 += __shfl_down(a2, off, 64);
    }
    if (lane == 0) {
        if (d < DIM) {
            WeffT[0 * DIM + d] = a0;
            WeffT[1 * DIM + d] = a1;
            WeffT[2 * DIM + d] = a2;
        } else {
            beff[0] = a0 + b2[0];
            beff[1] = a1 + b2[1];
            beff[2] = a2 + b2[2];
        }
    }
}

// ---------------------------------------------------------------------------
// Kernel 2 (R3: fully fused, barrier-free): ONE ROW PER WAVE.
//   - GEMV: 16 float4 x-loads/lane + cached WeffT, 6-step shuffle reduce,
//     t broadcast back to all lanes via __shfl (no LDS for t).
//   - Sigmoid pairs: 112 entries/wave into a private LDS strip.
//   - Same-wave lgkmcnt wait (NO __syncthreads anywhere).
//   - 784 coalesced float4 stores/wave; output retires via L2/L3.
// Combines R0's single-pass structure (no t4 HBM round-trip, one launch
// fewer than R2) with R2's barrier-free render. Expected ~11 us
// (x-read floor 10.3 us; writes absorbed by Infinity Cache).
// ---------------------------------------------------------------------------
__global__ __launch_bounds__(256) void fused_kernel(
    const float* __restrict__ x, const float* __restrict__ WeffT,
    const float* __restrict__ beff, float* __restrict__ out)
{
    __shared__ float sV[4][128];   // per-wave strip: Vx at [0], Vy at [64]

    const int tid  = threadIdx.x;
    const int wave = tid >> 6;
    const int lane = tid & 63;
    const int row  = blockIdx.x * 4 + wave;

    // ---- Phase A: GEMV for this wave's row ----
    const float* xr = x + (size_t)row * DIM + 4 * lane;
    float a0 = 0.f, a1 = 0.f, a2 = 0.f;
    #pragma unroll
    for (int q = 0; q < 4; ++q) {
        const int off = 256 * q;
        const floatx4 w0 = *(const floatx4*)(WeffT + 0 * DIM + 4 * lane + off);
        const floatx4 w1 = *(const floatx4*)(WeffT + 1 * DIM + 4 * lane + off);
        const floatx4 w2 = *(const floatx4*)(WeffT + 2 * DIM + 4 * lane + off);
        const floatx4 xv = *(const floatx4*)(xr + off);
        a0 += xv.x * w0.x + xv.y * w0.y + xv.z * w0.z + xv.w * w0.w;
        a1 += xv.x * w1.x + xv.y * w1.y + xv.z * w1.z + xv.w * w1.w;
        a2 += xv.x * w2.x + xv.y * w2.y + xv.z * w2.z + xv.w * w2.w;
    }
    #pragma unroll
    for (int off = 32; off; off >>= 1) {
        a0 += __shfl_down(a0, off, 64);
        a1 += __shfl_down(a1, off, 64);
        a2 += __shfl_down(a2, off, 64);
    }
    // Broadcast reduced t to all 64 lanes (no LDS, no barrier).
    const float t0 = __shfl(a0, 0, 64) + beff[0];
    const float t1 = __shfl(a1, 0, 64) + beff[1];
    const float t2 = __shfl(a2, 0, 64) + beff[2];
    const float hh = 0.5f * t2;

    // ---- Phase B: 112 sigmoid-pair entries into this wave's LDS strip ----
    #pragma unroll
    for (int p = 0; p < 2; ++p) {
        const int e = lane + 64 * p;
        if (e < 2 * MAP) {
            const int   isY = e >= MAP;
            const int   i   = isY ? e - MAP : e;
            const float tc  = isY ? t1 : t0;
            const float u   = (float)i - tc;
            const float pp  = 1.0f / (1.0f + __expf(-KST * (u + hh)));
            const float mm  = 1.0f / (1.0f + __expf(-KST * (u - hh)));
            sV[wave][(isY ? 64 : 0) + i] = pp - mm;
        }
    }
    // Same-wave LDS RAW only: wait for our own ds_writes; no cross-wave
    // hazard, so no __syncthreads.
    asm volatile("s_waitcnt lgkmcnt(0)" ::: "memory");

    // ---- Phase C: 784 coalesced float4 stores for this row ----
    floatx4* ob = (floatx4*)(out + (size_t)row * (MAP * MAP));
    const floatx4* vy4 = (const floatx4*)&sV[wave][64];
    for (int g = lane; g < MAP * MAP / 4; g += 64) {   // 784 = 12*64 + 16
        const int   i  = g / (MAP / 4);
        const int   jq = g - i * (MAP / 4);
        const float vx = sV[wave][i];
        const floatx4 vy = vy4[jq];
        floatx4 o;
        o.x = vx * vy.x; o.y = vx * vy.y; o.z = vx * vy.z; o.w = vx * vy.w;
        ob[g] = o;
    }
}

extern "C" void kernel_launch(void* const* d_in, const int* in_sizes, int n_in,
                              void* d_out, int out_size, void* d_ws, size_t ws_size,
                              hipStream_t stream) {
    const float* x  = (const float*)d_in[0];   // [16384, 1024]
    const float* W1 = (const float*)d_in[1];   // [1024, 512]
    const float* b1 = (const float*)d_in[2];   // [512]
    const float* W2 = (const float*)d_in[3];   // [512, 3]
    const float* b2 = (const float*)d_in[4];   // [3]
    float* out = (float*)d_out;                // [16384, 56, 56]

    float* WeffT = (float*)d_ws;               // 3*1024 floats
    float* beff  = WeffT + 3 * DIM;            // 3 floats

    fold_weights<<<DIM + 1, 64, 0, stream>>>(W1, b1, W2, b2, WeffT, beff);
    fused_kernel<<<BATCH / 4, 256, 0, stream>>>(x, WeffT, beff, out);
}